// Round 1
// baseline (102.678 us; speedup 1.0000x reference)
//
#include <hip/hip_runtime.h>
#include <hip/hip_bf16.h>

#define NI 32
#define B_POINTS 1048576
// log2(e)
#define L2E 1.44269504088896340736f

// Each thread processes 2 points (one float4 of the (B,2) array).
// Per map step:  t_i = exp(Y*Win_i + 2*bin_i);  gradV = sum_i w4_i * t_i/(1+t_i)^2
// with c1_i = Win_i*log2(e), e0_i = exp(2*bin_i), w4_i = 2*Win_i*Wout_i.
// Xout = Y + eta; Yout = gradV - X.

__global__ __launch_bounds__(256) void henon_kernel(
    const float* __restrict__ z,
    const float* __restrict__ Win,
    const float* __restrict__ Wout,
    const float* __restrict__ bin,
    const float* __restrict__ eta,
    float* __restrict__ out)
{
    __shared__ float4 cst[NI];   // (c1, e0, w4, pad)

    int t = threadIdx.x;
    if (t < NI) {
        float wi = Win[t];
        float c1 = wi * L2E;
        float e0 = __builtin_amdgcn_exp2f(bin[t] * (2.0f * L2E));  // exp(2*bin)
        float w4 = 2.0f * wi * Wout[t];
        cst[t] = make_float4(c1, e0, w4, 0.0f);
    }
    __syncthreads();

    float eta_v = eta[0];

    unsigned gid = blockIdx.x * blockDim.x + threadIdx.x;   // pair index
    float4 in = reinterpret_cast<const float4*>(z)[gid];    // (X0,Y0,X1,Y1)

    float Xa = in.x, Ya = in.y;
    float Xb = in.z, Yb = in.w;

#pragma unroll
    for (int it = 0; it < 4; ++it) {
        float ga = 0.0f, gb = 0.0f;
#pragma unroll
        for (int i = 0; i < NI; ++i) {
            float4 c = cst[i];
            float ta = __builtin_amdgcn_exp2f(Ya * c.x) * c.y;
            float tb = __builtin_amdgcn_exp2f(Yb * c.x) * c.y;
            float ra = ta + 1.0f;
            float rb = tb + 1.0f;
            float sa = __builtin_amdgcn_rcpf(ra);
            float sb = __builtin_amdgcn_rcpf(rb);
            ga = fmaf(c.z, ta * sa * sa, ga);
            gb = fmaf(c.z, tb * sb * sb, gb);
        }
        float Xoa = Ya + eta_v;
        float Xob = Yb + eta_v;
        float Yoa = ga - Xa;
        float Yob = gb - Xb;
        Xa = Xoa; Ya = Yoa;
        Xb = Xob; Yb = Yob;
    }

    float4 o = make_float4(Xa, Ya, Xb, Yb);
    reinterpret_cast<float4*>(out)[gid] = o;
}

extern "C" void kernel_launch(void* const* d_in, const int* in_sizes, int n_in,
                              void* d_out, int out_size, void* d_ws, size_t ws_size,
                              hipStream_t stream)
{
    const float* z    = (const float*)d_in[0];
    const float* Win  = (const float*)d_in[1];
    const float* Wout = (const float*)d_in[2];
    const float* bin  = (const float*)d_in[3];
    const float* eta  = (const float*)d_in[4];
    float* out = (float*)d_out;

    const int npairs = B_POINTS / 2;            // 524288 float4 groups
    const int block = 256;
    const int grid = npairs / block;            // 2048
    henon_kernel<<<grid, block, 0, stream>>>(z, Win, Wout, bin, eta, out);
}

// Round 2
// 70.758 us; speedup vs baseline: 1.4511x; 1.4511x over previous
//
#include <hip/hip_runtime.h>

#define NI 32
#define B_POINTS 1048576
#define L2E 1.44269504088896340736f

// gradV(Y) lookup table: TBL_N float2 entries {g_i, g_{i+1}-g_i} over [TBL_LO, -TBL_LO]
#define TBL_N 2048
#define TBL_LO (-32.0f)
#define TBL_SCALE 32.0f            // entries per unit of Y
#define TBL_BIAS 1024.0f           // -TBL_LO * TBL_SCALE
#define TBL_HMAX 2046.99f          // clamp so i <= TBL_N-2

// ---------------------------------------------------------------------------
// Producer: build gradV table in d_ws.  gradV(Y) = sum_i w_i * (1 - tanh^2(a_i)),
// a_i = (Y/2)*Win_i + bin_i, w_i = Win_i*Wout_i/2.  Using t = exp2(Y*Win*L2E + 2*bin*L2E):
// contribution = 2*Win*Wout * t/(1+t)^2.
// ---------------------------------------------------------------------------
__global__ __launch_bounds__(256) void henon_table_kernel(
    const float* __restrict__ Win, const float* __restrict__ Wout,
    const float* __restrict__ bin, float2* __restrict__ tbl)
{
    int t = blockIdx.x * 256 + threadIdx.x;          // 0 .. TBL_N-1
    float y0 = (float)t * (1.0f / TBL_SCALE) + TBL_LO;
    float y1 = y0 + (1.0f / TBL_SCALE);
    float g0 = 0.0f, g1 = 0.0f;
#pragma unroll 8
    for (int i = 0; i < NI; ++i) {
        float wi = Win[i];
        float c1 = wi * L2E;
        float e0 = __builtin_amdgcn_exp2f(bin[i] * (2.0f * L2E));
        float w4 = 2.0f * wi * Wout[i];
        float ta = __builtin_amdgcn_exp2f(y0 * c1) * e0;
        float tb = __builtin_amdgcn_exp2f(y1 * c1) * e0;
        float sa = __builtin_amdgcn_rcpf(ta + 1.0f);
        float sb = __builtin_amdgcn_rcpf(tb + 1.0f);
        g0 = fmaf(w4, ta * sa * sa, g0);
        g1 = fmaf(w4, tb * sb * sb, g1);
    }
    tbl[t] = make_float2(g0, g1 - g0);
}

// ---------------------------------------------------------------------------
// Consumer: stage table into LDS (16 KB), then 4 map iterations with one
// ds_read_b64 lerp per point per iteration.  2 points per thread (float4 I/O).
// ---------------------------------------------------------------------------
__global__ __launch_bounds__(256) void henon_main_kernel(
    const float* __restrict__ z, const float* __restrict__ eta,
    const float2* __restrict__ tbl, float* __restrict__ out)
{
    __shared__ float2 lt[TBL_N];                     // 16 KB

    // stage: 2048 float2 = 1024 float4; 256 threads x 4
    {
        const float4* src = reinterpret_cast<const float4*>(tbl);
        float4* dst = reinterpret_cast<float4*>(lt);
#pragma unroll
        for (int k = 0; k < 4; ++k)
            dst[threadIdx.x + 256 * k] = src[threadIdx.x + 256 * k];
    }

    float ev = eta[0];
    unsigned gid = blockIdx.x * 256 + threadIdx.x;   // pair index
    float4 in = reinterpret_cast<const float4*>(z)[gid];
    float Xa = in.x, Ya = in.y, Xb = in.z, Yb = in.w;

    __syncthreads();

#pragma unroll
    for (int it = 0; it < 4; ++it) {
        float ua = fmaf(Ya, TBL_SCALE, TBL_BIAS);
        float ub = fmaf(Yb, TBL_SCALE, TBL_BIAS);
        ua = fminf(fmaxf(ua, 0.0f), TBL_HMAX);
        ub = fminf(fmaxf(ub, 0.0f), TBL_HMAX);
        int ia = (int)ua, ib = (int)ub;
        float fa = ua - (float)ia;
        float fb = ub - (float)ib;
        float2 ea = lt[ia];
        float2 eb = lt[ib];
        float ga = fmaf(fa, ea.y, ea.x);
        float gb = fmaf(fb, eb.y, eb.x);
        float Xna = Ya + ev, Xnb = Yb + ev;
        float Yna = ga - Xa, Ynb = gb - Xb;
        Xa = Xna; Ya = Yna; Xb = Xnb; Yb = Ynb;
    }

    reinterpret_cast<float4*>(out)[gid] = make_float4(Xa, Ya, Xb, Yb);
}

extern "C" void kernel_launch(void* const* d_in, const int* in_sizes, int n_in,
                              void* d_out, int out_size, void* d_ws, size_t ws_size,
                              hipStream_t stream)
{
    const float* z    = (const float*)d_in[0];
    const float* Win  = (const float*)d_in[1];
    const float* Wout = (const float*)d_in[2];
    const float* bin  = (const float*)d_in[3];
    const float* eta  = (const float*)d_in[4];
    float* out = (float*)d_out;
    float2* tbl = (float2*)d_ws;                     // 16 KB used

    henon_table_kernel<<<TBL_N / 256, 256, 0, stream>>>(Win, Wout, bin, tbl);

    const int npairs = B_POINTS / 2;                 // 524288
    henon_main_kernel<<<npairs / 256, 256, 0, stream>>>(z, eta, tbl, out);
}

// Round 3
// 70.696 us; speedup vs baseline: 1.4524x; 1.0009x over previous
//
#include <hip/hip_runtime.h>

#define NI 32
#define B_POINTS 1048576
#define L2E 1.44269504088896340736f

// gradV lookup: 256-entry float table over Y in [-16, 16], h = 1/8.
// Lerp error ~ g''h^2/8 ~ 1e-5; |Y| provably <= ~14.5 through 4 iterations.
#define TBL_N 256
#define TBL_SCALE 8.0f
#define TBL_BIAS 128.0f
#define TBL_UMAX 254.999f   // index i <= 254, so gtab[i+1] <= gtab[255]

// One fused kernel: each block builds the 256-entry gradV table in LDS
// (1 entry/thread, 32 unit-evals each ~ 0.85us total chip-wide), then runs
// 4 map iterations on 4 points/thread with one ds_read2_b32 lerp per
// point-iteration.  gradV(Y) = sum_i 2*Win_i*Wout_i * t/(1+t)^2,
// t = exp(Y*Win_i + 2*bin_i).  Xout = Y + eta; Yout = gradV - X.
__global__ __launch_bounds__(256) void henon_fused_kernel(
    const float* __restrict__ z,
    const float* __restrict__ Win,
    const float* __restrict__ Wout,
    const float* __restrict__ bin,
    const float* __restrict__ eta,
    float* __restrict__ out)
{
    __shared__ float gtab[TBL_N];

    const int t = threadIdx.x;

    // ---- table phase: one entry per thread ----
    {
        float y = (float)t * (1.0f / TBL_SCALE) - 16.0f;
        float g = 0.0f;
#pragma unroll
        for (int i = 0; i < NI; ++i) {
            float wi = Win[i];
            float e0 = __builtin_amdgcn_exp2f(bin[i] * (2.0f * L2E)); // exp(2*bin)
            float tv = __builtin_amdgcn_exp2f(y * (wi * L2E)) * e0;   // exp(Y*Win+2*bin)
            float s  = __builtin_amdgcn_rcpf(tv + 1.0f);
            g = fmaf(2.0f * wi * Wout[i], tv * s * s, g);
        }
        gtab[t] = g;
    }

    // ---- load 2 float4 (4 points) per thread, coalesced ----
    const float ev = eta[0];
    const unsigned gid = blockIdx.x * 256u + (unsigned)t;   // 0..262143
    const float4* zin = reinterpret_cast<const float4*>(z);
    float4 p0 = zin[gid];
    float4 p1 = zin[gid + 262144u];

    float Xa = p0.x, Ya = p0.y, Xb = p0.z, Yb = p0.w;
    float Xc = p1.x, Yc = p1.y, Xd = p1.z, Yd = p1.w;

    __syncthreads();

    auto lookup = [&](float Y) -> float {
        float u = fmaf(Y, TBL_SCALE, TBL_BIAS);
        u = fminf(fmaxf(u, 0.0f), TBL_UMAX);
        int i = (int)u;
        float f = u - (float)i;
        float g0 = gtab[i];
        float g1 = gtab[i + 1];
        return fmaf(f, g1 - g0, g0);
    };

#pragma unroll
    for (int it = 0; it < 4; ++it) {
        float ga = lookup(Ya);
        float gb = lookup(Yb);
        float gc = lookup(Yc);
        float gd = lookup(Yd);
        float Xna = Ya + ev, Xnb = Yb + ev, Xnc = Yc + ev, Xnd = Yd + ev;
        float Yna = ga - Xa, Ynb = gb - Xb, Ync = gc - Xc, Ynd = gd - Xd;
        Xa = Xna; Ya = Yna; Xb = Xnb; Yb = Ynb;
        Xc = Xnc; Yc = Ync; Xd = Xnd; Yd = Ynd;
    }

    float4* o = reinterpret_cast<float4*>(out);
    o[gid]           = make_float4(Xa, Ya, Xb, Yb);
    o[gid + 262144u] = make_float4(Xc, Yc, Xd, Yd);
}

extern "C" void kernel_launch(void* const* d_in, const int* in_sizes, int n_in,
                              void* d_out, int out_size, void* d_ws, size_t ws_size,
                              hipStream_t stream)
{
    const float* z    = (const float*)d_in[0];
    const float* Win  = (const float*)d_in[1];
    const float* Wout = (const float*)d_in[2];
    const float* bin  = (const float*)d_in[3];
    const float* eta  = (const float*)d_in[4];
    float* out = (float*)d_out;

    // 262144 threads, 4 points each
    henon_fused_kernel<<<1024, 256, 0, stream>>>(z, Win, Wout, bin, eta, out);
}